// Round 2
// 133.092 us; speedup vs baseline: 1.0251x; 1.0251x over previous
//
#include <hip/hip_runtime.h>
#include <hip/hip_fp16.h>
#include <stdint.h>

// Problem constants (fixed by the reference):
#define MQ 8192   // N*C queries
#define NK 1024   // K codewords
#define DD 1024   // H*W
#define DELTA 2.0f  // screen slack: covers 2*(f16 score quant 0.5 + 5sigma arith 0.13)

typedef _Float16 half8_t __attribute__((ext_vector_type(8)));
typedef _Float16 half4_t __attribute__((ext_vector_type(4)));
typedef float    floatx4 __attribute__((ext_vector_type(4)));

// async global->LDS, 16B per lane; LDS dest is wave-uniform base + lane*16
#define GLOAD_LDS16(gp, lp)                                                   \
  __builtin_amdgcn_global_load_lds(                                           \
      (const __attribute__((address_space(1))) void*)(gp),                    \
      (__attribute__((address_space(3))) void*)(lp), 16, 0, 0)

// ---------- prep: f16 hi-parts only (screen needs no lo split) + csqr ----------
__global__ void k_prep(const float* __restrict__ x, const float* __restrict__ cb,
                       _Float16* __restrict__ ah, _Float16* __restrict__ bh,
                       float* __restrict__ csqr) {
  const int bid = blockIdx.x;
  const int t = threadIdx.x;
  if (bid < 8192) {
    int i = bid * 256 + t;
    float4 v = ((const float4*)x)[i];
    float vv[4] = {v.x, v.y, v.z, v.w};
    half4_t h;
#pragma unroll
    for (int j = 0; j < 4; ++j) h[j] = (_Float16)vv[j];
    ((half4_t*)ah)[i] = h;
  } else {
    int k = bid - 8192;
    float4 v = ((const float4*)(cb + (size_t)k * DD))[t];
    float vv[4] = {v.x, v.y, v.z, v.w};
    half4_t h;
    double s = 0.0;
#pragma unroll
    for (int j = 0; j < 4; ++j) {
      h[j] = (_Float16)vv[j];
      s += (double)vv[j] * (double)vv[j];
    }
    ((half4_t*)(bh + (size_t)k * DD))[t] = h;
    for (int m = 32; m >= 1; m >>= 1) s += __shfl_xor(s, m, 64);
    __shared__ double red[4];
    if ((t & 63) == 0) red[t >> 6] = s;
    __syncthreads();
    if (t == 0) csqr[k] = (float)(red[0] + red[1] + red[2] + red[3] - 1024.0);
  }
}

__device__ __forceinline__ unsigned sortable_u32(float f) {
  unsigned u = __float_as_uint(f);
  return (u & 0x80000000u) ? ~u : (u | 0x80000000u);
}

// ---------------- phase A: hi*hi screen GEMM, stores f16 score matrix ----------------
// S[m][n] = f16(csqr[n] - 2 * dot(xh[m], ch[n])) ; 128x128 tile
// 2-phase double-buffered K-loop (T3 minimal recipe: stage t+1 before
// compute t, ONE barrier per K-step) + XCD-chunked block swizzle (T1).
__global__ __launch_bounds__(256) void k_screen(
    const _Float16* __restrict__ Ah, const _Float16* __restrict__ Bh,
    const float* __restrict__ csqr, _Float16* __restrict__ S) {
  __shared__ _Float16 sA[2][128 * 32];  // row-major [row][32], unpadded
  __shared__ _Float16 sB[2][128 * 32];  // (global_load_lds forbids padding)

  const int tid = threadIdx.x;
  // 1-D grid of 512; HW assigns block wg -> XCD wg%8. Give each XCD a
  // contiguous chunk of 64 linear tiles (8 bm-rows x all 8 bn): A-panels are
  // then fetched into exactly one XCD's L2, and B (2MB) L2-fits per XCD.
  // 512 % 8 == 0 -> the simple swizzle is bijective.
  const int wg = blockIdx.x;
  const int sw = (wg & 7) * 64 + (wg >> 3);
  const int bm = sw >> 3;             // 0..63  (M tiles)
  const int bn = sw & 7;              // 0..7   (N tiles)
  const int m0 = bm * 128, n0 = bn * 128;
  const int wave = tid >> 6, lane = tid & 63;
  const int wm = wave & 1, wn = wave >> 1;
  const int quad = lane >> 4, l15 = lane & 15;

  floatx4 acc[4][4];
#pragma unroll
  for (int i = 0; i < 4; ++i)
#pragma unroll
    for (int j = 0; j < 4; ++j) acc[i][j] = (floatx4){0.f, 0.f, 0.f, 0.f};

  const int r0 = tid >> 2;
  const int c0 = (tid & 3) * 8;
  const size_t rowA  = (size_t)(m0 + r0) * DD + c0;
  const size_t rowA2 = (size_t)(m0 + 64 + r0) * DD + c0;
  const size_t rowB  = (size_t)(n0 + r0) * DD + c0;
  const size_t rowB2 = (size_t)(n0 + 64 + r0) * DD + c0;
  const int ldsoff = wave * 512;  // halfs; wave-linear order == row-major [r][32]

  auto stage = [&](int kk, int b) {
    GLOAD_LDS16(Ah + rowA + kk,  &sA[b][ldsoff]);
    GLOAD_LDS16(Ah + rowA2 + kk, &sA[b][2048 + ldsoff]);
    GLOAD_LDS16(Bh + rowB + kk,  &sB[b][ldsoff]);
    GLOAD_LDS16(Bh + rowB2 + kk, &sB[b][2048 + ldsoff]);
  };
  auto compute = [&](int c) {
    half8_t af[4], bf[4];
#pragma unroll
    for (int i = 0; i < 4; ++i)
      af[i] = *(const half8_t*)(&sA[c][(wm * 64 + i * 16 + l15) * 32 + quad * 8]);
#pragma unroll
    for (int j = 0; j < 4; ++j)
      bf[j] = *(const half8_t*)(&sB[c][(wn * 64 + j * 16 + l15) * 32 + quad * 8]);
#pragma unroll
    for (int i = 0; i < 4; ++i)
#pragma unroll
      for (int j = 0; j < 4; ++j)
        acc[i][j] = __builtin_amdgcn_mfma_f32_16x16x32_f16(af[i], bf[j], acc[i][j], 0, 0, 0);
  };

  // prologue: stage K-tile 0 into buf 0, drain, barrier
  stage(0, 0);
  __syncthreads();

  int cur = 0;
  for (int kb = 0; kb < 31; ++kb) {
    stage((kb + 1) * 32, cur ^ 1);  // issue next-tile loads FIRST (overlap)
    compute(cur);                   // ds_read + 16 MFMA hide the load latency
    __syncthreads();                // one vmcnt(0)+lgkmcnt(0)+barrier per K-step
    cur ^= 1;
  }
  compute(cur);  // last tile, no prefetch; no barrier needed before epilogue

  // epilogue: write f16 approx scores (no atomics, no keys)
  float csv[4];
#pragma unroll
  for (int j = 0; j < 4; ++j) csv[j] = csqr[n0 + wn * 64 + j * 16 + l15];
#pragma unroll
  for (int i = 0; i < 4; ++i)
#pragma unroll
    for (int r = 0; r < 4; ++r) {
      const int row = m0 + wm * 64 + i * 16 + quad * 4 + r;  // C/D: col=lane&15, row=quad*4+reg
#pragma unroll
      for (int j = 0; j < 4; ++j) {
        const int col = n0 + wn * 64 + j * 16 + l15;
        S[(size_t)row * NK + col] = (_Float16)(csv[j] - 2.0f * acc[i][j][r]);
      }
    }
}

// -------- phase B: wave-per-row scan + exact fp32 refine + gather/write --------
__global__ __launch_bounds__(256) void k_refine(
    const _Float16* __restrict__ S, const float* __restrict__ x,
    const float* __restrict__ cb, float* __restrict__ out, int both) {
  const int wave = threadIdx.x >> 6, lane = threadIdx.x & 63;
  const int m = blockIdx.x * 4 + wave;

  // scan score row: 16 f16 per lane
  const half8_t* Srow = (const half8_t*)(S + (size_t)m * NK);
  half8_t s0 = Srow[lane * 2];
  half8_t s1 = Srow[lane * 2 + 1];
  float sc[16];
#pragma unroll
  for (int k = 0; k < 8; ++k) { sc[k] = (float)s0[k]; sc[8 + k] = (float)s1[k]; }
  float mn = sc[0];
#pragma unroll
  for (int k = 1; k < 16; ++k) mn = fminf(mn, sc[k]);
  for (int o = 1; o <= 32; o <<= 1) mn = fminf(mn, __shfl_xor(mn, o, 64));
  const float thr = mn + DELTA;

  // collect candidate indices (wave-uniform list in registers)
  int cand[12];
  int nc = 0;
#pragma unroll
  for (int s = 0; s < 16; ++s) {
    unsigned long long msk = __ballot(sc[s] <= thr);
    while (msk && nc < 12) {
      int l = __builtin_ctzll(msk);
      msk &= msk - 1;
      cand[nc++] = l * 16 + s;  // lane l holds cols l*16 + s
    }
  }

  // Fast path: nc is wave-uniform (built from ballots). With DELTA=2 the
  // screen isolates a unique winner for ~94% of rows -> skip the x re-read
  // (32MB of HBM) and the exact fp32 refine entirely.
  int widx;
  if (nc == 1) {
    widx = cand[0];
  } else {
    // x row in registers: lane covers floats [q*256 + lane*4, +4)
    const float4* xr4 = (const float4*)(x + (size_t)m * DD);
    float4 xr[4];
#pragma unroll
    for (int q = 0; q < 4; ++q) xr[q] = xr4[q * 64 + lane];

    // exact fp32 refine over candidates
    unsigned long long best = ~0ULL;
    for (int c = 0; c < nc; ++c) {
      const float4* c4 = (const float4*)(cb + (size_t)cand[c] * DD);
      float d = 0.f;
#pragma unroll
      for (int q = 0; q < 4; ++q) {
        float4 v = c4[q * 64 + lane];
        float dx = xr[q].x - v.x, dy = xr[q].y - v.y;
        float dz = xr[q].z - v.z, dw = xr[q].w - v.w;
        d += dx * dx + dy * dy + dz * dz + dw * dw;
      }
      for (int o = 1; o <= 32; o <<= 1) d += __shfl_xor(d, o, 64);
      unsigned long long key =
          ((unsigned long long)sortable_u32(d) << 32) | (unsigned)cand[c];
      best = key < best ? key : best;  // ties -> lowest index (np argmin)
    }
    widx = (int)(best & 0xFFFFFFFFULL);
  }

  // gather winner (cb is 4MB -> L3-hot), write output(s) nontemporally:
  // outputs are write-once-never-read, keep them out of L2 so S/cb stay hot.
  // NOTE: __builtin_nontemporal_store requires a clang ext-vector type, not
  // HIP's float4 struct -> go through floatx4.
  const floatx4* w4 = (const floatx4*)(cb + (size_t)widx * DD);
  floatx4* o0 = (floatx4*)(out + (size_t)m * DD);
  floatx4* o1 = (floatx4*)(out + (size_t)(m + MQ) * DD);
#pragma unroll
  for (int q = 0; q < 4; ++q) {
    floatx4 v = w4[q * 64 + lane];
    __builtin_nontemporal_store(v, &o0[q * 64 + lane]);
    if (both) __builtin_nontemporal_store(v, &o1[q * 64 + lane]);
  }
}

// d2d copy lower output copy -> upper (only when S had to live in d_out's top)
__global__ void k_copy(const floatx4* __restrict__ src, floatx4* __restrict__ dst) {
  int i = blockIdx.x * 256 + threadIdx.x;
  __builtin_nontemporal_store(src[i], &dst[i]);
}

extern "C" void kernel_launch(void* const* d_in, const int* in_sizes, int n_in,
                              void* d_out, int out_size, void* d_ws, size_t ws_size,
                              hipStream_t stream) {
  const float* x = (const float*)d_in[0];
  const float* cb = (const float*)d_in[1];
  float* out = (float*)d_out;
  char* ob = (char*)d_out;

  const size_t MB = 1024 * 1024;
  // Ah/Bh scratch lives in d_out (dead before any output write).
  _Float16* Ah = (_Float16*)(ob);              // [0,16MB)
  _Float16* Bh = (_Float16*)(ob + 16 * MB);    // [16,18MB)

  // S (16MB) + csqr (4KB): prefer d_ws if it's big enough (NEVER assume — R1
  // overflow corrupted harness pristine inputs). Fallback: S in d_out[48,64MB),
  // refine then writes only the lower output copy and k_copy fills the upper.
  const bool ws_ok = ws_size >= 16 * MB + 4096;
  _Float16* S;
  float* csqr;
  if (ws_ok) {
    S = (_Float16*)d_ws;
    csqr = (float*)((char*)d_ws + 16 * MB);
  } else {
    S = (_Float16*)(ob + 48 * MB);
    csqr = (float*)(ob + 18 * MB);
  }

  k_prep<<<8192 + 1024, 256, 0, stream>>>(x, cb, Ah, Bh, csqr);
  k_screen<<<512, 256, 0, stream>>>(Ah, Bh, csqr, S);
  k_refine<<<2048, 256, 0, stream>>>(S, x, cb, out, ws_ok ? 1 : 0);
  if (!ws_ok) k_copy<<<8192, 256, 0, stream>>>((const floatx4*)out, (floatx4*)(ob + 32 * MB));
}